// Round 1
// 110.445 us; speedup vs baseline: 1.0741x; 1.0741x over previous
//
#include <hip/hip_runtime.h>
#include <math.h>

#define EPS 1e-6f
constexpr int B    = 64;
constexpr int F    = 2;
constexpr int NC   = 10;
constexpr int ND   = 4;
constexpr int CHW  = 64 * 16 * 16;   // 16384
constexpr int FCHW = F * CHW;        // 32768
constexpr int SBLK = 256;
constexpr int NBLK_S = CHW / SBLK;   // 64

__device__ __forceinline__ float log_sigmoid(float x) {
    // jax.nn.log_sigmoid: -log1p(exp(-x)), stabilized
    return fminf(x, 0.0f) - log1pf(expf(-fabsf(x)));
}

// Kernel A: fused segment-sum (bins) + means/lnm + per-block norm partials.
// grid (NBLK_S, NC), block SBLK. Each block reads only the x_LE rows whose
// label == nc, so x_LE is read exactly once across the whole grid.
__global__ void k_fused_means(const float* __restrict__ xLE, const int* __restrict__ labels,
                              const float* __restrict__ w1, const float* __restrict__ miu,
                              const float* __restrict__ tao, const float* __restrict__ sigmas,
                              const float* __restrict__ Xw, const float* __restrict__ XLEs,
                              float* __restrict__ mt   /* [NC][CHW] */,
                              float* __restrict__ lnm  /* [NC][CHW] */,
                              float* __restrict__ pnorm/* [NC][NBLK_S][ND] */) {
    __shared__ int lab[B];
    int tid = threadIdx.x;
    if (tid < B) lab[tid] = labels[tid];
    __syncthreads();

    int s  = blockIdx.x * SBLK + tid;   // [0, CHW)
    int nc = blockIdx.y;

    // segment-sum over the batch, restricted to this nc (wave-uniform branch)
    int   cint = 0;
    float bin0 = XLEs[nc * FCHW + s];
    float bin1 = XLEs[nc * FCHW + CHW + s];
    for (int b = 0; b < B; ++b) {
        if (lab[b] == nc) {
            ++cint;
            bin0 += xLE[b * FCHW + s];          // coalesced
            bin1 += xLE[b * FCHW + CHW + s];
        }
    }
    float cnt     = Xw[nc] + (float)cint;
    float inv_cnt = 1.0f / cnt;

    float w1sq[ND];
    float s1 = 0.0f;
#pragma unroll
    for (int nd = 0; nd < ND; ++nd) { float t = w1[nd]; w1sq[nd] = t * t; s1 += t * t; }
    float inv_s1 = 1.0f / s1;
    float sg   = sigmas[nc];
    float sig2 = sg * sg;

    float xb0 = bin0 * inv_cnt;
    float xb1 = bin1 * inv_cnt;
    float ls0  = log_sigmoid(xb0);
    float ls1  = log_sigmoid(xb1);
    float ls1e = log_sigmoid(xb1 + EPS);

    float psum[ND];
    float theta = 0.0f, magm = 0.0f;
#pragma unroll
    for (int nd = 0; nd < ND; ++nd) {
        float m0 = miu[nd * FCHW + s];
        float m1 = miu[nd * FCHW + CHW + s];
        float d0 = ls0 - log_sigmoid(m0);
        float d1 = ls1 - log_sigmoid(m1);
        psum[nd] = d0 * d0 + d1 * d1;

        float tv   = tao[nd];
        float tao2 = tv * tv;
        float denom = 1.0f / (sig2 + tao2);
        float rt = tao2 * denom;
        float rs = sig2 * denom;
        float wn = w1sq[nd] * inv_s1;      // w1n == w2n in the reference
        theta += (xb1 * rt + m0 * rs) * wn;
        magm  += expf((rt * ls1e + rs * log_sigmoid(m1 + EPS)) * wn);
    }
    mt[nc * CHW + s]  = theta;
    lnm[nc * CHW + s] = logf(magm + EPS);

    // block-level reduction of psum -> per-block partial (no atomics, no zero-init)
#pragma unroll
    for (int nd = 0; nd < ND; ++nd) {
        float v = psum[nd];
        for (int off = 32; off > 0; off >>= 1)
            v += __shfl_down(v, off, 64);
        psum[nd] = v;
    }
    __shared__ float red[4][ND];
    int lane = tid & 63;
    int wv   = tid >> 6;
    if (lane == 0) {
#pragma unroll
        for (int nd = 0; nd < ND; ++nd) red[wv][nd] = psum[nd];
    }
    __syncthreads();
    if (tid < ND) {
        int nd = tid;
        pnorm[(nc * NBLK_S + blockIdx.x) * ND + nd] =
            red[0][nd] + red[1][nd] + red[2][nd] + red[3][nd];
    }
}

// Kernel B: x_out + (block 0 only) loss from norm partials.
__global__ void k_xout_loss(const float* __restrict__ xLE, const float* __restrict__ mt,
                            const float* __restrict__ lnm, const float* __restrict__ weight,
                            const int* __restrict__ labels, const float* __restrict__ Xw,
                            const float* __restrict__ tao, const float* __restrict__ sigmas,
                            const float* __restrict__ pnorm,
                            float* __restrict__ out /* [B*CHW] xout, then [ND] loss */) {
    int idx = blockIdx.x * blockDim.x + threadIdx.x;  // [0, B*CHW)
    int b = idx >> 14;
    int s = idx & (CHW - 1);
    float x0 = xLE[b * FCHW + s];
    float x1 = xLE[b * FCHW + CHW + s];
    float lnx1 = logf(x1);
    float wv0 = weight[0], wv1 = weight[1];
    float w0 = wv0 * wv0, w1s = wv1 * wv1;
    float best = INFINITY;
#pragma unroll
    for (int nc = 0; nc < NC; ++nc) {
        float dr = fabsf(x0 - mt[nc * CHW + s]);
        float da = fabsf(lnx1 - lnm[nc * CHW + s]);
        float d = w0 * dr + w1s * da;
        best = fminf(best, d);
    }
    out[idx] = best;

    if (blockIdx.x == 0 && threadIdx.x < ND) {
        int nd = threadIdx.x;
        float tv   = tao[nd];
        float tao2 = tv * tv;
        float tao4 = tao2 * tao2;
        float acc = 0.0f;
        for (int nc = 0; nc < NC; ++nc) {
            int cint = 0;
            for (int bb = 0; bb < B; ++bb) cint += (labels[bb] == nc);
            float cnt  = Xw[nc] + (float)cint;
            float sg   = sigmas[nc];
            float sig2 = sg * sg;
            float normv = 0.0f;
            for (int blk = 0; blk < NBLK_S; ++blk)
                normv += pnorm[(nc * NBLK_S + blk) * ND + nd];
            float t1 = sig2 / ((tao2 + sig2) * (tao2 + sig2));
            float t2 = sig2 * normv;
            float t3 = 2.0f * (float)CHW * (tao4 - sig2 * sig2) / cnt;
            acc += t1 * (t2 + t3);
        }
        out[B * CHW + nd] = acc / (float)NC;
    }
}

extern "C" void kernel_launch(void* const* d_in, const int* in_sizes, int n_in,
                              void* d_out, int out_size, void* d_ws, size_t ws_size,
                              hipStream_t stream) {
    const float* xLE    = (const float*)d_in[0];
    const int*   labels = (const int*)  d_in[1];
    const float* w1     = (const float*)d_in[2];
    // d_in[3] (w2) is unused: the reference computes w2n from w1.
    const float* miu    = (const float*)d_in[4];
    const float* tao    = (const float*)d_in[5];
    const float* weight = (const float*)d_in[6];
    const float* sigmas = (const float*)d_in[7];
    const float* XLEs   = (const float*)d_in[8];
    const float* Xw     = (const float*)d_in[9];

    float* out = (float*)d_out;                 // x_out [B*CHW] then loss [ND]

    float* mt    = (float*)d_ws;                // NC*CHW
    float* lnm   = mt + NC * CHW;               // NC*CHW
    float* pnorm = lnm + NC * CHW;              // NC*NBLK_S*ND

    k_fused_means<<<dim3(NBLK_S, NC), SBLK, 0, stream>>>(
        xLE, labels, w1, miu, tao, sigmas, Xw, XLEs, mt, lnm, pnorm);

    k_xout_loss<<<(B * CHW) / 256, 256, 0, stream>>>(
        xLE, mt, lnm, weight, labels, Xw, tao, sigmas, pnorm, out);
}